// Round 16
// baseline (483.302 us; speedup 1.0000x reference)
//
#include <hip/hip_runtime.h>
#include <math.h>

#define NEG_SLOPE 0.2f
#define BUCKET_BITS 9
#define BUCKET_SZ (1 << BUCKET_BITS)
#define PREP_BLOCKS 10

typedef unsigned short u16;
typedef float f32x4 __attribute__((ext_vector_type(4)));
typedef short s16x8 __attribute__((ext_vector_type(8)));

__device__ __forceinline__ u16 f2bf(float f) {
    unsigned u = __float_as_uint(f);
    unsigned r = (u + 0x7FFF + ((u >> 16) & 1)) >> 16;
    return (u16)r;
}
__device__ __forceinline__ float bf2f(u16 v) {
    return __uint_as_float((unsigned)v << 16);
}
__device__ __forceinline__ unsigned cvt_pk_bf16(float a, float b) {
    unsigned r;
    asm("v_cvt_pk_bf16_f32 %0, %1, %2" : "=v"(r) : "v"(a), "v"(b));
    return r;
}
#define SWZ(u, row) ((u) ^ (((row) & 7) << 3))

// device-scope grid barrier: safe because grid == co-resident capacity (engineered below)
__device__ __forceinline__ void gridbar(int* gcnt, int target, int t) {
    __syncthreads();
    if (t == 0) {
        __threadfence();
        __hip_atomic_fetch_add(gcnt, 1, __ATOMIC_RELEASE, __HIP_MEMORY_SCOPE_AGENT);
        long guard = 0;
        while (__hip_atomic_load(gcnt, __ATOMIC_ACQUIRE, __HIP_MEMORY_SCOPE_AGENT) < target) {
            __builtin_amdgcn_s_sleep(8);
            if (++guard > (1L << 26)) break;   // safety valve: degrade, never hang
        }
        __threadfence();
    }
    __syncthreads();
}

__global__ __launch_bounds__(512, 6) void mega(const float* __restrict__ x,
                                               const int* __restrict__ src,
                                               const int* __restrict__ dst,
                                               const float* __restrict__ W1,
                                               const float* __restrict__ al1,
                                               const float* __restrict__ ar1,
                                               const float* __restrict__ b1,
                                               const float* __restrict__ W2,
                                               const float* __restrict__ al2,
                                               const float* __restrict__ ar2,
                                               const float* __restrict__ b2,
                                               float* __restrict__ out,
                                               u16* __restrict__ W1bT, u16* __restrict__ W2bT,
                                               u16* __restrict__ feat1b, u16* __restrict__ hb,
                                               u16* __restrict__ feat2b,
                                               float* __restrict__ el1, float* __restrict__ er1,
                                               float* __restrict__ el2, float* __restrict__ er2,
                                               int* __restrict__ row_start, int* __restrict__ csr_src,
                                               int* __restrict__ bucket_cursor, int* __restrict__ gbar,
                                               unsigned* __restrict__ staging,
                                               int N, int E, int NB, int cap, int nsc, int nblk) {
    __shared__ __align__(16) u16 ws[144 * 128];   // 36.9KB (gemm1 tile; build/gemm2 carve it)
    __shared__ float us_[8][64][4];               // 8KB  (agg1, wave-private)
    __shared__ int sns_[8][64];                   // 2KB
    __shared__ int cnt_[256], rbase_[256];        // 2KB  (scatter)
    __shared__ int shv[2];
    int t = threadIdx.x;
    int bid = blockIdx.x;
    int nb1 = (N + 127) / 128;

    // ---------------- P1: scatter (vb<nsc) + weight prep -------------------
    for (int vb = bid; vb < nsc + PREP_BLOCKS; vb += nblk) {
        __syncthreads();
        if (vb < nsc) {
            if (t < NB) cnt_[t] = 0;
            __syncthreads();
            int base_e = vb * 4096;
            int d[8], s[8];
#pragma unroll
            for (int q = 0; q < 2; ++q) {
                int e0 = base_e + q * 2048 + t * 4;
                int4 dv = make_int4(-1, -1, -1, -1), sv = make_int4(0, 0, 0, 0);
                if (e0 + 3 < E) {
                    dv = *(const int4*)&dst[e0];
                    sv = *(const int4*)&src[e0];
                } else if (e0 < E) {
                    int m = E - e0;
                    for (int j = 0; j < m; ++j) { ((int*)&dv)[j] = dst[e0 + j]; ((int*)&sv)[j] = src[e0 + j]; }
                }
                *(int4*)&d[q * 4] = dv;
                *(int4*)&s[q * 4] = sv;
            }
#pragma unroll
            for (int it = 0; it < 8; ++it)
                if (d[it] >= 0) atomicAdd(&cnt_[d[it] >> BUCKET_BITS], 1);
            __syncthreads();
            if (t < NB && cnt_[t] > 0) rbase_[t] = atomicAdd(&bucket_cursor[t], cnt_[t]);
            __syncthreads();
#pragma unroll
            for (int it = 0; it < 8; ++it) {
                if (d[it] >= 0) {
                    int b = d[it] >> BUCKET_BITS;
                    int pos = atomicAdd(&rbase_[b], 1);
                    if (pos < cap)
                        staging[(size_t)b * cap + pos] =
                            ((unsigned)(d[it] & (BUCKET_SZ - 1)) << 17) | ((unsigned)s[it] & 0x1FFFFu);
                }
            }
        } else {
            int gt = (vb - nsc) * 512 + t;
            int stride = PREP_BLOCKS * 512;
            for (int idx = gt; idx < 144 * 128; idx += stride) {
                int c = idx >> 7, k = idx & 127;
                float v = 0.f;
                if (c < 128) v = W1[k * 128 + c];
                else if (c < 132) {
                    int h = c - 128; float sum = 0.f;
                    for (int dd = 0; dd < 32; ++dd) sum += W1[k * 128 + h * 32 + dd] * al1[h * 32 + dd];
                    v = sum;
                } else if (c < 136) {
                    int h = c - 132; float sum = 0.f;
                    for (int dd = 0; dd < 32; ++dd) sum += W1[k * 128 + h * 32 + dd] * ar1[h * 32 + dd];
                    v = sum;
                }
                W1bT[idx] = f2bf(v);
            }
            for (int idx = gt; idx < 32 * 128; idx += stride) {
                int c = idx >> 7, k = idx & 127;
                float v = 0.f;
                if (c < 16) v = W2[k * 16 + c];
                else if (c == 16) { float sum = 0.f; for (int dd = 0; dd < 16; ++dd) sum += W2[k * 16 + dd] * al2[dd]; v = sum; }
                else if (c == 17) { float sum = 0.f; for (int dd = 0; dd < 16; ++dd) sum += W2[k * 16 + dd] * ar2[dd]; v = sum; }
                W2bT[idx] = f2bf(v);
            }
        }
    }
    gridbar(gbar, nblk, t);

    // ---------------- P2: build (vb<NB) + gemm1 ---------------------------
    for (int vb = bid; vb < NB + nb1; vb += nblk) {
        __syncthreads();
        if (vb < NB) {
            int* deg = (int*)ws;
            int* cur = deg + 512;
            int* tmp = cur + 512;
            int b = vb;
            int v = (t < NB) ? bucket_cursor[t] : 0;
            tmp[t] = v;
            __syncthreads();
            for (int off = 1; off < 512; off <<= 1) {
                int x2 = (t >= off) ? tmp[t - off] : 0;
                __syncthreads();
                tmp[t] += x2;
                __syncthreads();
            }
            if (t == b) { shv[0] = tmp[t] - v; shv[1] = min(v, cap); }
            if (b == 0 && t == 0) row_start[N] = E;
            __syncthreads();
            int cbase = shv[0], cntv = shv[1];
            int node0 = b << BUCKET_BITS;
            int nn = min(BUCKET_SZ, N - node0);
            deg[t] = 0;
            __syncthreads();
            const unsigned* st = &staging[(size_t)b * cap];
            for (int i = t; i < cntv; i += 512) atomicAdd(&deg[st[i] >> 17], 1);
            __syncthreads();
            int a0 = (t < nn) ? deg[t] : 0;
            tmp[t] = a0;
            __syncthreads();
            for (int off = 1; off < 512; off <<= 1) {
                int x2 = (t >= off) ? tmp[t - off] : 0;
                __syncthreads();
                tmp[t] += x2;
                __syncthreads();
            }
            int excl = tmp[t] - a0;
            if (t < nn) { row_start[node0 + t] = cbase + excl; cur[t] = excl; }
            __syncthreads();
            for (int i = t; i < cntv; i += 512) {
                unsigned e = st[i];
                int p = atomicAdd(&cur[e >> 17], 1);
                csr_src[cbase + p] = (int)(e & 0x1FFFFu);
            }
        } else {
            int base = (vb - NB) * 128;
            for (int idx = t; idx < 2304; idx += 512) {
                int c = idx >> 4, k8 = (idx & 15) * 8;
                *(s16x8*)&ws[SWZ(c * 128 + k8, c)] = *(const s16x8*)&W1bT[c * 128 + k8];
            }
            int wid = t >> 6, lane = t & 63;
            int lr = lane & 15, lg = lane >> 4;
            int row0 = wid * 16;
            int grow = base + row0 + lr;
            bool rowok = grow < N;
            int crow = rowok ? grow : 0;
            s16x8 afr[4];
#pragma unroll
            for (int kt = 0; kt < 4; ++kt) {
                const float4* px = (const float4*)&x[(size_t)crow * 128 + kt * 32 + lg * 8];
                float4 v0 = px[0], v1 = px[1];
                unsigned p[4] = {cvt_pk_bf16(v0.x, v0.y), cvt_pk_bf16(v0.z, v0.w),
                                 cvt_pk_bf16(v1.x, v1.y), cvt_pk_bf16(v1.z, v1.w)};
                if (!rowok) { p[0] = p[1] = p[2] = p[3] = 0; }
                afr[kt] = *(s16x8*)p;
            }
            __syncthreads();
            f32x4 acc[9];
#pragma unroll
            for (int ct = 0; ct < 9; ++ct) acc[ct] = (f32x4){0.f, 0.f, 0.f, 0.f};
#pragma unroll
            for (int ct = 0; ct < 9; ++ct) {
#pragma unroll
                for (int kt = 0; kt < 4; ++kt) {
                    int c = ct * 16 + lr, k = kt * 32 + lg * 8;
                    s16x8 bfr = *(const s16x8*)&ws[SWZ(c * 128 + k, c)];
                    acc[ct] = __builtin_amdgcn_mfma_f32_16x16x32_bf16(afr[kt], bfr, acc[ct], 0, 0, 0);
                }
            }
#pragma unroll
            for (int ct = 0; ct < 9; ++ct) {
#pragma unroll
                for (int r = 0; r < 4; ++r) {
                    int row = base + row0 + lg * 4 + r;
                    if (row >= N) continue;
                    float v = acc[ct][r];
                    if (ct < 8) {
                        feat1b[(size_t)row * 128 + ct * 16 + lr] = f2bf(v);
                    } else {
                        if (lr < 4) el1[row * 4 + lr] = v;
                        else if (lr < 8) er1[row * 4 + (lr - 4)] = v;
                    }
                }
            }
        }
    }
    gridbar(gbar, 2 * nblk, t);

    // ---------------- P3: agg1 (8 nodes/block-group, wave-private) --------
    {
        int wid = t >> 6, lane = t & 63;
        int slot = lane >> 4, dg = lane & 15;
        int h = dg >> 2;
        int ngroups = (N + 7) >> 3;
        for (int grp = bid; grp < ngroups; grp += nblk) {
            int node = grp * 8 + wid;
            if (node >= N) continue;
            int rs = row_start[node], re = row_start[node + 1];
            float4 er4 = *(const float4*)&er1[node * 4];
            float acc[8] = {};
            float z = 0.f;
            for (int ts = rs; ts < re; ts += 64) {
                int cntv = min(64, re - ts);
                if (lane < cntv) {
                    int sn = min(max(csr_src[ts + lane], 0), N - 1);
                    sns_[wid][lane] = sn;
                    float4 elv = *(const float4*)&el1[sn * 4];
                    float e0 = elv.x + er4.x, e1 = elv.y + er4.y;
                    float e2 = elv.z + er4.z, e3 = elv.w + er4.w;
                    e0 = e0 > 0.f ? e0 : NEG_SLOPE * e0;
                    e1 = e1 > 0.f ? e1 : NEG_SLOPE * e1;
                    e2 = e2 > 0.f ? e2 : NEG_SLOPE * e2;
                    e3 = e3 > 0.f ? e3 : NEG_SLOPE * e3;
                    *(float4*)&us_[wid][lane][0] =
                        make_float4(__expf(fminf(e0, 60.f)), __expf(fminf(e1, 60.f)),
                                    __expf(fminf(e2, 60.f)), __expf(fminf(e3, 60.f)));
                }
                for (int e0i = 0; e0i < cntv; e0i += 8) {
                    int ea = e0i + slot, eb = e0i + 4 + slot;
                    bool va = ea < cntv, vb2 = eb < cntv;
                    int ia = va ? ea : 0, ib = vb2 ? eb : 0;
                    int sa = sns_[wid][ia], sb = sns_[wid][ib];
                    float wa = va ? us_[wid][ia][h] : 0.f;
                    float wb = vb2 ? us_[wid][ib][h] : 0.f;
                    uint4 fa = *(const uint4*)&feat1b[(size_t)sa * 128 + dg * 8];
                    uint4 fb = *(const uint4*)&feat1b[(size_t)sb * 128 + dg * 8];
                    acc[0] += wa * __uint_as_float(fa.x << 16);
                    acc[1] += wa * __uint_as_float(fa.x & 0xffff0000u);
                    acc[2] += wa * __uint_as_float(fa.y << 16);
                    acc[3] += wa * __uint_as_float(fa.y & 0xffff0000u);
                    acc[4] += wa * __uint_as_float(fa.z << 16);
                    acc[5] += wa * __uint_as_float(fa.z & 0xffff0000u);
                    acc[6] += wa * __uint_as_float(fa.w << 16);
                    acc[7] += wa * __uint_as_float(fa.w & 0xffff0000u);
                    z += wa;
                    acc[0] += wb * __uint_as_float(fb.x << 16);
                    acc[1] += wb * __uint_as_float(fb.x & 0xffff0000u);
                    acc[2] += wb * __uint_as_float(fb.y << 16);
                    acc[3] += wb * __uint_as_float(fb.y & 0xffff0000u);
                    acc[4] += wb * __uint_as_float(fb.z << 16);
                    acc[5] += wb * __uint_as_float(fb.z & 0xffff0000u);
                    acc[6] += wb * __uint_as_float(fb.w << 16);
                    acc[7] += wb * __uint_as_float(fb.w & 0xffff0000u);
                    z += wb;
                }
            }
#pragma unroll
            for (int i = 0; i < 8; ++i) {
                acc[i] += __shfl_xor(acc[i], 16);
                acc[i] += __shfl_xor(acc[i], 32);
            }
            z += __shfl_xor(z, 16);
            z += __shfl_xor(z, 32);
            if (slot == 0) {
                float inv = (z > 0.f) ? 1.f / z : 0.f;
                float4 b0 = *(const float4*)&b1[dg * 8];
                float4 b4 = *(const float4*)&b1[dg * 8 + 4];
                float vv[8] = {acc[0] * inv + b0.x, acc[1] * inv + b0.y,
                               acc[2] * inv + b0.z, acc[3] * inv + b0.w,
                               acc[4] * inv + b4.x, acc[5] * inv + b4.y,
                               acc[6] * inv + b4.z, acc[7] * inv + b4.w};
                u16 o[8];
#pragma unroll
                for (int i = 0; i < 8; ++i) {
                    float v = vv[i] > 0.f ? vv[i] : expm1f(vv[i]);
                    o[i] = f2bf(v);
                }
                *(s16x8*)&hb[(size_t)node * 128 + dg * 8] = *(s16x8*)o;
            }
        }
    }
    gridbar(gbar, 3 * nblk, t);

    // ---------------- P4: gemm2 -------------------------------------------
    for (int vb = bid; vb < nb1; vb += nblk) {
        __syncthreads();
        int base = vb * 128;
        {
            int c = t >> 4, k8 = (t & 15) * 8;
            *(s16x8*)&ws[SWZ(c * 128 + k8, c)] = *(const s16x8*)&W2bT[c * 128 + k8];
        }
        int wid = t >> 6, lane = t & 63;
        int lr = lane & 15, lg = lane >> 4;
        int row0 = wid * 16;
        int grow = base + row0 + lr;
        bool rowok = grow < N;
        int crow = rowok ? grow : 0;
        s16x8 afr[4];
#pragma unroll
        for (int kt = 0; kt < 4; ++kt) {
            s16x8 v = *(const s16x8*)&hb[(size_t)crow * 128 + kt * 32 + lg * 8];
            if (!rowok) v = (s16x8){0, 0, 0, 0, 0, 0, 0, 0};
            afr[kt] = v;
        }
        __syncthreads();
        f32x4 acc[2];
        acc[0] = (f32x4){0.f, 0.f, 0.f, 0.f};
        acc[1] = acc[0];
#pragma unroll
        for (int ct = 0; ct < 2; ++ct) {
#pragma unroll
            for (int kt = 0; kt < 4; ++kt) {
                int c = ct * 16 + lr, k = kt * 32 + lg * 8;
                s16x8 bfr = *(const s16x8*)&ws[SWZ(c * 128 + k, c)];
                acc[ct] = __builtin_amdgcn_mfma_f32_16x16x32_bf16(afr[kt], bfr, acc[ct], 0, 0, 0);
            }
        }
#pragma unroll
        for (int ct = 0; ct < 2; ++ct) {
#pragma unroll
            for (int r = 0; r < 4; ++r) {
                int row = base + row0 + lg * 4 + r;
                if (row >= N) continue;
                float v = acc[ct][r];
                if (ct == 0) {
                    feat2b[(size_t)row * 16 + lr] = f2bf(v);
                } else {
                    if (lr == 0) el2[row] = v;
                    else if (lr == 1) er2[row] = v;
                }
            }
        }
    }
    gridbar(gbar, 4 * nblk, t);

    // ---------------- P5: agg2 (16 nodes/group, LDS-free) -----------------
    {
        int wid = t >> 6, lane = t & 63;
        int sub = lane >> 5;
        int slot = (lane >> 2) & 7;
        int dq = lane & 3;
        int ngroups = (N + 15) >> 4;
        for (int grp = bid; grp < ngroups; grp += nblk) {
            int node = grp * 16 + wid * 2 + sub;
            if (node >= N) continue;
            int rs = row_start[node], re = row_start[node + 1];
            float er_n = er2[node];
            float a0 = 0.f, a1 = 0.f, a2 = 0.f, a3 = 0.f, z = 0.f;
            for (int ts = rs; ts < re; ts += 16) {
                int ea = ts + slot, eb = ts + 8 + slot;
                bool va = ea < re, vb2 = eb < re;
                int sa = va ? csr_src[ea] : 0;
                int sb = vb2 ? csr_src[eb] : 0;
                sa = min(max(sa, 0), N - 1);
                sb = min(max(sb, 0), N - 1);
                float eva = el2[sa] + er_n;
                float evb = el2[sb] + er_n;
                uint2 fa = *(const uint2*)&feat2b[(size_t)sa * 16 + dq * 4];
                uint2 fb = *(const uint2*)&feat2b[(size_t)sb * 16 + dq * 4];
                eva = eva > 0.f ? eva : NEG_SLOPE * eva;
                evb = evb > 0.f ? evb : NEG_SLOPE * evb;
                float wa = va ? __expf(fminf(eva, 60.f)) : 0.f;
                float wb = vb2 ? __expf(fminf(evb, 60.f)) : 0.f;
                a0 += wa * __uint_as_float(fa.x << 16) + wb * __uint_as_float(fb.x << 16);
                a1 += wa * __uint_as_float(fa.x & 0xffff0000u) + wb * __uint_as_float(fb.x & 0xffff0000u);
                a2 += wa * __uint_as_float(fa.y << 16) + wb * __uint_as_float(fb.y << 16);
                a3 += wa * __uint_as_float(fa.y & 0xffff0000u) + wb * __uint_as_float(fb.y & 0xffff0000u);
                z += wa + wb;
            }
#pragma unroll
            for (int o = 4; o <= 16; o <<= 1) {
                a0 += __shfl_xor(a0, o);
                a1 += __shfl_xor(a1, o);
                a2 += __shfl_xor(a2, o);
                a3 += __shfl_xor(a3, o);
                z += __shfl_xor(z, o);
            }
            if (slot == 0) {
                float inv = (z > 0.f) ? 1.f / z : 0.f;
                float4 bv = *(const float4*)&b2[dq * 4];
                *(float4*)&out[(size_t)node * 16 + dq * 4] =
                    make_float4(a0 * inv + bv.x, a1 * inv + bv.y, a2 * inv + bv.z, a3 * inv + bv.w);
            }
        }
    }
}

// ---------------------------------------------------------------- launch
extern "C" void kernel_launch(void* const* d_in, const int* in_sizes, int n_in,
                              void* d_out, int out_size, void* d_ws, size_t ws_size,
                              hipStream_t stream) {
    const float* x   = (const float*)d_in[0];
    const int*   src = (const int*)d_in[1];
    const int*   dst = (const int*)d_in[2];
    const float* W1  = (const float*)d_in[3];
    const float* al1 = (const float*)d_in[4];
    const float* ar1 = (const float*)d_in[5];
    const float* b1  = (const float*)d_in[6];
    const float* W2  = (const float*)d_in[7];
    const float* al2 = (const float*)d_in[8];
    const float* ar2 = (const float*)d_in[9];
    const float* b2  = (const float*)d_in[10];
    float* out = (float*)d_out;

    const int N = in_sizes[0] / 128;
    const int E = in_sizes[1];
    const int NB = (N + BUCKET_SZ - 1) >> BUCKET_BITS;
    const int cap = ((2 * (E / NB)) + 255) & ~255;

    char* p = (char*)d_ws;
    auto alloc = [&](size_t bytes) {
        char* r = p;
        p += (bytes + 255) & ~(size_t)255;
        return r;
    };
    u16* W1bT   = (u16*)alloc(144 * 128 * 2);
    u16* W2bT   = (u16*)alloc(32 * 128 * 2);
    u16* feat1b = (u16*)alloc((size_t)N * 128 * 2);
    u16* hb     = (u16*)alloc((size_t)N * 128 * 2);
    u16* feat2b = (u16*)alloc((size_t)N * 16 * 2);
    float* el1  = (float*)alloc((size_t)N * 4 * 4);
    float* er1  = (float*)alloc((size_t)N * 4 * 4);
    float* el2v = (float*)alloc((size_t)N * 4);
    float* er2v = (float*)alloc((size_t)N * 4);
    int* row_start     = (int*)alloc((size_t)(N + 1) * 4);
    int* csr_src       = (int*)alloc((size_t)E * 4);
    int* bucket_cursor = (int*)alloc((size_t)(NB + 1) * 4);   // +1: grid-barrier counter
    int* gbar          = bucket_cursor + NB;
    unsigned* staging  = (unsigned*)alloc((size_t)NB * cap * 4);

    // zero cursors + barrier counter (one node)
    (void)hipMemsetAsync(bucket_cursor, 0, (size_t)(NB + 1) * 4, stream);

    // engineered co-residency: 3 blocks/CU (LDS 51KB, VGPR capped by launch_bounds)
    hipDeviceProp_t prop;
    (void)hipGetDeviceProperties(&prop, 0);
    int maxb = 0;
    (void)hipOccupancyMaxActiveBlocksPerMultiprocessor(&maxb, mega, 512, 0);
    if (maxb < 1) maxb = 1;
    if (maxb > 3) maxb = 3;
    int nblk = maxb * prop.multiProcessorCount;

    int nsc = (E + 4095) / 4096;
    mega<<<nblk, 512, 0, stream>>>(x, src, dst, W1, al1, ar1, b1, W2, al2, ar2, b2, out,
                                   W1bT, W2bT, feat1b, hb, feat2b,
                                   el1, er1, el2v, er2v,
                                   row_start, csr_src, bucket_cursor, gbar, staging,
                                   N, E, NB, cap, nsc, nblk);
}

// Round 17
// 177.935 us; speedup vs baseline: 2.7162x; 2.7162x over previous
//
#include <hip/hip_runtime.h>
#include <math.h>

#define NEG_SLOPE 0.2f
#define BUCKET_BITS 9
#define BUCKET_SZ (1 << BUCKET_BITS)

typedef unsigned short u16;
typedef float f32x4 __attribute__((ext_vector_type(4)));
typedef short s16x8 __attribute__((ext_vector_type(8)));

__device__ __forceinline__ u16 f2bf(float f) {
    unsigned u = __float_as_uint(f);
    unsigned r = (u + 0x7FFF + ((u >> 16) & 1)) >> 16;
    return (u16)r;
}
__device__ __forceinline__ float bf2f(u16 v) {
    return __uint_as_float((unsigned)v << 16);
}
__device__ __forceinline__ unsigned cvt_pk_bf16(float a, float b) {
    unsigned r;
    asm("v_cvt_pk_bf16_f32 %0, %1, %2" : "=v"(r) : "v"(a), "v"(b));
    return r;
}
// ushort-index XOR swizzle: conflict-free b128 col reads
#define SWZ(u, row) ((u) ^ (((row) & 7) << 3))

#define PREP_BLOCKS 10

// ---------------------------------------------------------------- b_scatter (2048 edges/block) + fused weight prep
__global__ __launch_bounds__(256) void scatter_prep(const int* __restrict__ src,
                                                    const int* __restrict__ dst,
                                                    int* __restrict__ bucket_cursor,
                                                    unsigned* __restrict__ staging,
                                                    int E, int NB, int cap, int nsc,
                                                    const float* __restrict__ W1,
                                                    const float* __restrict__ al1,
                                                    const float* __restrict__ ar1,
                                                    const float* __restrict__ W2,
                                                    const float* __restrict__ al2,
                                                    const float* __restrict__ ar2,
                                                    u16* __restrict__ W1bT,
                                                    u16* __restrict__ W2bT) {
    int t = threadIdx.x;
    if (blockIdx.x >= nsc) {
        int gt = (blockIdx.x - nsc) * 256 + t;
        int stride = PREP_BLOCKS * 256;
        for (int idx = gt; idx < 144 * 128; idx += stride) {
            int c = idx >> 7, k = idx & 127;
            float v = 0.f;
            if (c < 128) v = W1[k * 128 + c];
            else if (c < 132) {
                int h = c - 128; float s = 0.f;
                for (int d = 0; d < 32; ++d) s += W1[k * 128 + h * 32 + d] * al1[h * 32 + d];
                v = s;
            } else if (c < 136) {
                int h = c - 132; float s = 0.f;
                for (int d = 0; d < 32; ++d) s += W1[k * 128 + h * 32 + d] * ar1[h * 32 + d];
                v = s;
            }
            W1bT[idx] = f2bf(v);
        }
        for (int idx = gt; idx < 32 * 128; idx += stride) {
            int c = idx >> 7, k = idx & 127;
            float v = 0.f;
            if (c < 16) v = W2[k * 16 + c];
            else if (c == 16) { float s = 0.f; for (int d = 0; d < 16; ++d) s += W2[k * 16 + d] * al2[d]; v = s; }
            else if (c == 17) { float s = 0.f; for (int d = 0; d < 16; ++d) s += W2[k * 16 + d] * ar2[d]; v = s; }
            W2bT[idx] = f2bf(v);
        }
        return;
    }
    __shared__ int cnt[256], rbase[256];
    if (t < NB) cnt[t] = 0;
    __syncthreads();
    int base_e = blockIdx.x * 2048;
    int d[8], s[8];
#pragma unroll
    for (int q = 0; q < 2; ++q) {
        int e0 = base_e + q * 1024 + t * 4;
        int4 dv = make_int4(-1, -1, -1, -1), sv = make_int4(0, 0, 0, 0);
        if (e0 + 3 < E) {
            dv = *(const int4*)&dst[e0];
            sv = *(const int4*)&src[e0];
        } else if (e0 < E) {
            int m = E - e0;
            for (int j = 0; j < m; ++j) { ((int*)&dv)[j] = dst[e0 + j]; ((int*)&sv)[j] = src[e0 + j]; }
        }
        *(int4*)&d[q * 4] = dv;
        *(int4*)&s[q * 4] = sv;
    }
#pragma unroll
    for (int it = 0; it < 8; ++it)
        if (d[it] >= 0) atomicAdd(&cnt[d[it] >> BUCKET_BITS], 1);
    __syncthreads();
    if (t < NB && cnt[t] > 0) rbase[t] = atomicAdd(&bucket_cursor[t], cnt[t]);
    __syncthreads();
#pragma unroll
    for (int it = 0; it < 8; ++it) {
        if (d[it] >= 0) {
            int b = d[it] >> BUCKET_BITS;
            int pos = atomicAdd(&rbase[b], 1);   // rbase doubles as running cursor
            if (pos < cap)
                staging[(size_t)b * cap + pos] =
                    ((unsigned)(d[it] & (BUCKET_SZ - 1)) << 17) | ((unsigned)s[it] & 0x1FFFFu);
        }
    }
}

// ---------------------------------------------------------------- fused: b_build blocks [0,nbuild) || gemm1 blocks [nbuild, nbuild+nb1)
__global__ __launch_bounds__(512) void build_gemm1(const unsigned* __restrict__ staging,
                                                   const int* __restrict__ bucket_cursor,
                                                   int* __restrict__ row_start,
                                                   int* __restrict__ csr_src, int N, int E,
                                                   int NB, int cap, int nbuild,
                                                   const float* __restrict__ x,
                                                   const u16* __restrict__ W1bT,
                                                   u16* __restrict__ featb,
                                                   float* __restrict__ el,
                                                   float* __restrict__ er) {
    __shared__ u16 ws[144 * 128];
    __shared__ int sh_cbase, sh_cnt;
    int t = threadIdx.x;
    if (blockIdx.x < nbuild) {
        int* deg = (int*)ws;
        int* cur = deg + 512;
        int* tmp = cur + 512;
        int b = blockIdx.x;
        int v = (t < NB) ? bucket_cursor[t] : 0;
        tmp[t] = v;
        __syncthreads();
        for (int off = 1; off < 512; off <<= 1) {
            int x2 = (t >= off) ? tmp[t - off] : 0;
            __syncthreads();
            tmp[t] += x2;
            __syncthreads();
        }
        if (t == b) { sh_cbase = tmp[t] - v; sh_cnt = min(v, cap); }
        if (b == 0 && t == 0) row_start[N] = E;
        __syncthreads();
        int cbase = sh_cbase, cnt = sh_cnt;
        int node0 = b << BUCKET_BITS;
        int nn = min(BUCKET_SZ, N - node0);
        deg[t] = 0;
        __syncthreads();
        const unsigned* st = &staging[(size_t)b * cap];
        for (int i = t; i < cnt; i += 512) atomicAdd(&deg[st[i] >> 17], 1);
        __syncthreads();
        int a0 = (t < nn) ? deg[t] : 0;
        tmp[t] = a0;
        __syncthreads();
        for (int off = 1; off < 512; off <<= 1) {
            int x2 = (t >= off) ? tmp[t - off] : 0;
            __syncthreads();
            tmp[t] += x2;
            __syncthreads();
        }
        int excl = tmp[t] - a0;
        if (t < nn) { row_start[node0 + t] = cbase + excl; cur[t] = excl; }
        __syncthreads();
        for (int i = t; i < cnt; i += 512) {
            unsigned e = st[i];
            int p = atomicAdd(&cur[e >> 17], 1);
            csr_src[cbase + p] = (int)(e & 0x1FFFFu);
        }
        return;
    }
    int base = (blockIdx.x - nbuild) * 128;
    for (int idx = t; idx < 2304; idx += 512) {
        int c = idx >> 4, k8 = (idx & 15) * 8;
        *(s16x8*)&ws[SWZ(c * 128 + k8, c)] = *(const s16x8*)&W1bT[c * 128 + k8];
    }
    int wid = t >> 6, lane = t & 63;
    int lr = lane & 15, lg = lane >> 4;
    int row0 = wid * 16;
    int grow = base + row0 + lr;
    bool rowok = grow < N;
    int crow = rowok ? grow : 0;
    s16x8 afr[4];
#pragma unroll
    for (int kt = 0; kt < 4; ++kt) {
        const float4* px = (const float4*)&x[(size_t)crow * 128 + kt * 32 + lg * 8];
        float4 v0 = px[0], v1 = px[1];
        unsigned p[4] = {cvt_pk_bf16(v0.x, v0.y), cvt_pk_bf16(v0.z, v0.w),
                         cvt_pk_bf16(v1.x, v1.y), cvt_pk_bf16(v1.z, v1.w)};
        if (!rowok) { p[0] = p[1] = p[2] = p[3] = 0; }
        afr[kt] = *(s16x8*)p;
    }
    __syncthreads();
    f32x4 acc[9];
#pragma unroll
    for (int ct = 0; ct < 9; ++ct) acc[ct] = (f32x4){0.f, 0.f, 0.f, 0.f};
#pragma unroll
    for (int ct = 0; ct < 9; ++ct) {
#pragma unroll
        for (int kt = 0; kt < 4; ++kt) {
            int c = ct * 16 + lr, k = kt * 32 + lg * 8;
            s16x8 bfr = *(const s16x8*)&ws[SWZ(c * 128 + k, c)];
            acc[ct] = __builtin_amdgcn_mfma_f32_16x16x32_bf16(afr[kt], bfr, acc[ct], 0, 0, 0);
        }
    }
#pragma unroll
    for (int ct = 0; ct < 9; ++ct) {
#pragma unroll
        for (int r = 0; r < 4; ++r) {
            int row = base + row0 + lg * 4 + r;
            if (row >= N) continue;
            float v = acc[ct][r];
            if (ct < 8) {
                featb[(size_t)row * 128 + ct * 16 + lr] = f2bf(v);
            } else {
                if (lr < 4) el[row * 4 + lr] = v;
                else if (lr < 8) er[row * 4 + (lr - 4)] = v;
            }
        }
    }
}

// ---------------------------------------------------------------- agg layer 1: 512 threads, 8 nodes/block (same per-wave shape as r8)
__global__ __launch_bounds__(512) void agg1(const int* __restrict__ row_start,
                                            const int* __restrict__ csr_src,
                                            const float* __restrict__ el1,
                                            const float* __restrict__ er1,
                                            const u16* __restrict__ featb,
                                            const float* __restrict__ b1,
                                            u16* __restrict__ hb, int n) {
    __shared__ float us[8][64][4];   // [wave][edge][head]
    __shared__ int sns[8][64];
    int wid = threadIdx.x >> 6, lane = threadIdx.x & 63;
    int node = blockIdx.x * 8 + wid;
    if (node >= n) return;
    int slot = lane >> 4, dg = lane & 15;
    int h = dg >> 2;
    int rs = row_start[node], re = row_start[node + 1];
    float4 er4 = *(const float4*)&er1[node * 4];
    float acc[8] = {};
    float z = 0.f;
    for (int ts = rs; ts < re; ts += 64) {
        int cnt = min(64, re - ts);
        if (lane < cnt) {
            int sn = min(max(csr_src[ts + lane], 0), n - 1);
            sns[wid][lane] = sn;
            float4 elv = *(const float4*)&el1[sn * 4];
            float e0 = elv.x + er4.x, e1 = elv.y + er4.y;
            float e2 = elv.z + er4.z, e3 = elv.w + er4.w;
            e0 = e0 > 0.f ? e0 : NEG_SLOPE * e0;
            e1 = e1 > 0.f ? e1 : NEG_SLOPE * e1;
            e2 = e2 > 0.f ? e2 : NEG_SLOPE * e2;
            e3 = e3 > 0.f ? e3 : NEG_SLOPE * e3;
            *(float4*)&us[wid][lane][0] =
                make_float4(__expf(fminf(e0, 60.f)), __expf(fminf(e1, 60.f)),
                            __expf(fminf(e2, 60.f)), __expf(fminf(e3, 60.f)));
        }
        for (int e0i = 0; e0i < cnt; e0i += 8) {
            int ea = e0i + slot, eb = e0i + 4 + slot;
            bool va = ea < cnt, vb = eb < cnt;
            int ia = va ? ea : 0, ib = vb ? eb : 0;
            int sa = sns[wid][ia], sb = sns[wid][ib];
            float wa = va ? us[wid][ia][h] : 0.f;
            float wb = vb ? us[wid][ib][h] : 0.f;
            uint4 fa = *(const uint4*)&featb[(size_t)sa * 128 + dg * 8];
            uint4 fb = *(const uint4*)&featb[(size_t)sb * 128 + dg * 8];
            acc[0] += wa * __uint_as_float(fa.x << 16);
            acc[1] += wa * __uint_as_float(fa.x & 0xffff0000u);
            acc[2] += wa * __uint_as_float(fa.y << 16);
            acc[3] += wa * __uint_as_float(fa.y & 0xffff0000u);
            acc[4] += wa * __uint_as_float(fa.z << 16);
            acc[5] += wa * __uint_as_float(fa.z & 0xffff0000u);
            acc[6] += wa * __uint_as_float(fa.w << 16);
            acc[7] += wa * __uint_as_float(fa.w & 0xffff0000u);
            z += wa;
            acc[0] += wb * __uint_as_float(fb.x << 16);
            acc[1] += wb * __uint_as_float(fb.x & 0xffff0000u);
            acc[2] += wb * __uint_as_float(fb.y << 16);
            acc[3] += wb * __uint_as_float(fb.y & 0xffff0000u);
            acc[4] += wb * __uint_as_float(fb.z << 16);
            acc[5] += wb * __uint_as_float(fb.z & 0xffff0000u);
            acc[6] += wb * __uint_as_float(fb.w << 16);
            acc[7] += wb * __uint_as_float(fb.w & 0xffff0000u);
            z += wb;
        }
    }
#pragma unroll
    for (int i = 0; i < 8; ++i) {
        acc[i] += __shfl_xor(acc[i], 16);
        acc[i] += __shfl_xor(acc[i], 32);
    }
    z += __shfl_xor(z, 16);
    z += __shfl_xor(z, 32);
    if (slot == 0) {
        float inv = (z > 0.f) ? 1.f / z : 0.f;
        float4 b0 = *(const float4*)&b1[dg * 8];
        float4 b4 = *(const float4*)&b1[dg * 8 + 4];
        float vv[8] = {acc[0] * inv + b0.x, acc[1] * inv + b0.y,
                       acc[2] * inv + b0.z, acc[3] * inv + b0.w,
                       acc[4] * inv + b4.x, acc[5] * inv + b4.y,
                       acc[6] * inv + b4.z, acc[7] * inv + b4.w};
        u16 o[8];
#pragma unroll
        for (int i = 0; i < 8; ++i) {
            float v = vv[i] > 0.f ? vv[i] : expm1f(vv[i]);
            o[i] = f2bf(v);
        }
        *(s16x8*)&hb[(size_t)node * 128 + dg * 8] = *(s16x8*)o;
    }
}

// ---------------------------------------------------------------- GEMM2 (MFMA): 512 threads, 128-row blocks (r15 version)
__global__ __launch_bounds__(512) void gemm2_mfma(const u16* __restrict__ hb,
                                                  const u16* __restrict__ W2bT,
                                                  u16* __restrict__ feat2b,
                                                  float* __restrict__ el2,
                                                  float* __restrict__ er2, int n) {
    __shared__ u16 ws[32 * 128];
    int t = threadIdx.x;
    int base = blockIdx.x * 128;
    {
        int c = t >> 4, k8 = (t & 15) * 8;
        *(s16x8*)&ws[SWZ(c * 128 + k8, c)] = *(const s16x8*)&W2bT[c * 128 + k8];
    }
    int wid = t >> 6, lane = t & 63;
    int lr = lane & 15, lg = lane >> 4;
    int row0 = wid * 16;
    int grow = base + row0 + lr;
    bool rowok = grow < n;
    int crow = rowok ? grow : 0;
    s16x8 afr[4];
#pragma unroll
    for (int kt = 0; kt < 4; ++kt) {
        s16x8 v = *(const s16x8*)&hb[(size_t)crow * 128 + kt * 32 + lg * 8];
        if (!rowok) v = (s16x8){0, 0, 0, 0, 0, 0, 0, 0};
        afr[kt] = v;
    }
    __syncthreads();
    f32x4 acc[2];
    acc[0] = (f32x4){0.f, 0.f, 0.f, 0.f};
    acc[1] = acc[0];
#pragma unroll
    for (int ct = 0; ct < 2; ++ct) {
#pragma unroll
        for (int kt = 0; kt < 4; ++kt) {
            int c = ct * 16 + lr, k = kt * 32 + lg * 8;
            s16x8 bfr = *(const s16x8*)&ws[SWZ(c * 128 + k, c)];
            acc[ct] = __builtin_amdgcn_mfma_f32_16x16x32_bf16(afr[kt], bfr, acc[ct], 0, 0, 0);
        }
    }
#pragma unroll
    for (int ct = 0; ct < 2; ++ct) {
#pragma unroll
        for (int r = 0; r < 4; ++r) {
            int row = base + row0 + lg * 4 + r;
            if (row >= n) continue;
            float v = acc[ct][r];
            if (ct == 0) {
                feat2b[(size_t)row * 16 + lr] = f2bf(v);
            } else {
                if (lr == 0) el2[row] = v;
                else if (lr == 1) er2[row] = v;
            }
        }
    }
}

// ---------------------------------------------------------------- agg layer 2: 2 nodes/wave, 2-edge unroll, grid-stride (r14/r15 version)
__global__ __launch_bounds__(256) void agg2(const int* __restrict__ row_start,
                                            const int* __restrict__ csr_src,
                                            const float* __restrict__ el2,
                                            const float* __restrict__ er2,
                                            const u16* __restrict__ feat2b,
                                            const float* __restrict__ b2,
                                            float* __restrict__ out, int n) {
    int t = threadIdx.x;
    int wid = t >> 6, lane = t & 63;
    int sub = lane >> 5;
    int slot = (lane >> 2) & 7;
    int dq = lane & 3;
    int ngroups = (n + 7) >> 3;
    for (int grp = blockIdx.x; grp < ngroups; grp += gridDim.x) {
        int node = grp * 8 + wid * 2 + sub;
        if (node >= n) continue;
        int rs = row_start[node], re = row_start[node + 1];
        float er_n = er2[node];
        float a0 = 0.f, a1 = 0.f, a2 = 0.f, a3 = 0.f, z = 0.f;
        for (int ts = rs; ts < re; ts += 16) {
            int ea = ts + slot, eb = ts + 8 + slot;
            bool va = ea < re, vb = eb < re;
            int sa = va ? csr_src[ea] : 0;
            int sb = vb ? csr_src[eb] : 0;
            sa = min(max(sa, 0), n - 1);
            sb = min(max(sb, 0), n - 1);
            float eva = el2[sa] + er_n;
            float evb = el2[sb] + er_n;
            uint2 fa = *(const uint2*)&feat2b[(size_t)sa * 16 + dq * 4];
            uint2 fb = *(const uint2*)&feat2b[(size_t)sb * 16 + dq * 4];
            eva = eva > 0.f ? eva : NEG_SLOPE * eva;
            evb = evb > 0.f ? evb : NEG_SLOPE * evb;
            float wa = va ? __expf(fminf(eva, 60.f)) : 0.f;
            float wb = vb ? __expf(fminf(evb, 60.f)) : 0.f;
            a0 += wa * __uint_as_float(fa.x << 16) + wb * __uint_as_float(fb.x << 16);
            a1 += wa * __uint_as_float(fa.x & 0xffff0000u) + wb * __uint_as_float(fb.x & 0xffff0000u);
            a2 += wa * __uint_as_float(fa.y << 16) + wb * __uint_as_float(fb.y << 16);
            a3 += wa * __uint_as_float(fa.y & 0xffff0000u) + wb * __uint_as_float(fb.y & 0xffff0000u);
            z += wa + wb;
        }
#pragma unroll
        for (int o = 4; o <= 16; o <<= 1) {
            a0 += __shfl_xor(a0, o);
            a1 += __shfl_xor(a1, o);
            a2 += __shfl_xor(a2, o);
            a3 += __shfl_xor(a3, o);
            z += __shfl_xor(z, o);
        }
        if (slot == 0) {
            float inv = (z > 0.f) ? 1.f / z : 0.f;
            float4 bv = *(const float4*)&b2[dq * 4];
            *(float4*)&out[(size_t)node * 16 + dq * 4] =
                make_float4(a0 * inv + bv.x, a1 * inv + bv.y, a2 * inv + bv.z, a3 * inv + bv.w);
        }
    }
}

// ---------------------------------------------------------------- launch
extern "C" void kernel_launch(void* const* d_in, const int* in_sizes, int n_in,
                              void* d_out, int out_size, void* d_ws, size_t ws_size,
                              hipStream_t stream) {
    const float* x   = (const float*)d_in[0];
    const int*   src = (const int*)d_in[1];
    const int*   dst = (const int*)d_in[2];
    const float* W1  = (const float*)d_in[3];
    const float* al1 = (const float*)d_in[4];
    const float* ar1 = (const float*)d_in[5];
    const float* b1  = (const float*)d_in[6];
    const float* W2  = (const float*)d_in[7];
    const float* al2 = (const float*)d_in[8];
    const float* ar2 = (const float*)d_in[9];
    const float* b2  = (const float*)d_in[10];
    float* out = (float*)d_out;

    const int N = in_sizes[0] / 128;
    const int E = in_sizes[1];
    const int NB = (N + BUCKET_SZ - 1) >> BUCKET_BITS;
    const int cap = ((2 * (E / NB)) + 255) & ~255;

    char* p = (char*)d_ws;
    auto alloc = [&](size_t bytes) {
        char* r = p;
        p += (bytes + 255) & ~(size_t)255;
        return r;
    };
    u16* W1bT   = (u16*)alloc(144 * 128 * 2);
    u16* W2bT   = (u16*)alloc(32 * 128 * 2);
    u16* feat1b = (u16*)alloc((size_t)N * 128 * 2);
    u16* hb     = (u16*)alloc((size_t)N * 128 * 2);
    u16* feat2b = (u16*)alloc((size_t)N * 16 * 2);
    float* el1  = (float*)alloc((size_t)N * 4 * 4);
    float* er1  = (float*)alloc((size_t)N * 4 * 4);
    float* el2v = (float*)alloc((size_t)N * 4);
    float* er2v = (float*)alloc((size_t)N * 4);
    int* row_start     = (int*)alloc((size_t)(N + 1) * 4);
    int* csr_src       = (int*)alloc((size_t)E * 4);
    int* bucket_cursor = (int*)alloc((size_t)NB * 4);
    unsigned* staging  = (unsigned*)alloc((size_t)NB * cap * 4);

    (void)hipMemsetAsync(bucket_cursor, 0, (size_t)NB * 4, stream);

    int nsc = (E + 2047) / 2048;
    scatter_prep<<<nsc + PREP_BLOCKS, 256, 0, stream>>>(src, dst, bucket_cursor, staging,
                                                        E, NB, cap, nsc,
                                                        W1, al1, ar1, W2, al2, ar2, W1bT, W2bT);

    int nb1 = (N + 127) / 128;
    build_gemm1<<<NB + nb1, 512, 0, stream>>>(staging, bucket_cursor, row_start, csr_src,
                                              N, E, NB, cap, NB,
                                              x, W1bT, feat1b, el1, er1);

    int nodeblk8 = (N + 7) / 8;
    agg1<<<nodeblk8, 512, 0, stream>>>(row_start, csr_src, el1, er1, feat1b, b1, hb, N);
    gemm2_mfma<<<nb1, 512, 0, stream>>>(hb, W2bT, feat2b, el2v, er2v, N);
    agg2<<<2048, 256, 0, stream>>>(row_start, csr_src, el2v, er2v, feat2b, b2, out, N);
}

// Round 18
// 164.999 us; speedup vs baseline: 2.9291x; 1.0784x over previous
//
#include <hip/hip_runtime.h>
#include <math.h>

#define NEG_SLOPE 0.2f
#define BUCKET_BITS 9
#define BUCKET_SZ (1 << BUCKET_BITS)

typedef unsigned short u16;
typedef float f32x4 __attribute__((ext_vector_type(4)));
typedef short s16x8 __attribute__((ext_vector_type(8)));

__device__ __forceinline__ u16 f2bf(float f) {
    unsigned u = __float_as_uint(f);
    unsigned r = (u + 0x7FFF + ((u >> 16) & 1)) >> 16;
    return (u16)r;
}
__device__ __forceinline__ float bf2f(u16 v) {
    return __uint_as_float((unsigned)v << 16);
}
__device__ __forceinline__ unsigned cvt_pk_bf16(float a, float b) {
    unsigned r;
    asm("v_cvt_pk_bf16_f32 %0, %1, %2" : "=v"(r) : "v"(a), "v"(b));
    return r;
}
// ushort-index XOR swizzle: conflict-free b128 col reads
#define SWZ(u, row) ((u) ^ (((row) & 7) << 3))

#define PREP_BLOCKS 10

// ---------------------------------------------------------------- b_scatter + fused prep (r12/r13 version)
__global__ __launch_bounds__(256) void scatter_prep(const int* __restrict__ src,
                                                    const int* __restrict__ dst,
                                                    int* __restrict__ bucket_cursor,
                                                    unsigned* __restrict__ staging,
                                                    int E, int NB, int cap, int nsc,
                                                    const float* __restrict__ W1,
                                                    const float* __restrict__ al1,
                                                    const float* __restrict__ ar1,
                                                    const float* __restrict__ W2,
                                                    const float* __restrict__ al2,
                                                    const float* __restrict__ ar2,
                                                    u16* __restrict__ W1bT,
                                                    u16* __restrict__ W2bT) {
    int t = threadIdx.x;
    if (blockIdx.x >= nsc) {
        int gt = (blockIdx.x - nsc) * 256 + t;
        int stride = PREP_BLOCKS * 256;
        for (int idx = gt; idx < 144 * 128; idx += stride) {
            int c = idx >> 7, k = idx & 127;
            float v = 0.f;
            if (c < 128) v = W1[k * 128 + c];
            else if (c < 132) {
                int h = c - 128; float s = 0.f;
                for (int d = 0; d < 32; ++d) s += W1[k * 128 + h * 32 + d] * al1[h * 32 + d];
                v = s;
            } else if (c < 136) {
                int h = c - 132; float s = 0.f;
                for (int d = 0; d < 32; ++d) s += W1[k * 128 + h * 32 + d] * ar1[h * 32 + d];
                v = s;
            }
            W1bT[idx] = f2bf(v);
        }
        for (int idx = gt; idx < 32 * 128; idx += stride) {
            int c = idx >> 7, k = idx & 127;
            float v = 0.f;
            if (c < 16) v = W2[k * 16 + c];
            else if (c == 16) { float s = 0.f; for (int d = 0; d < 16; ++d) s += W2[k * 16 + d] * al2[d]; v = s; }
            else if (c == 17) { float s = 0.f; for (int d = 0; d < 16; ++d) s += W2[k * 16 + d] * ar2[d]; v = s; }
            W2bT[idx] = f2bf(v);
        }
        return;
    }
    __shared__ int cnt[256], rbase[256];
    if (t < NB) cnt[t] = 0;
    __syncthreads();
    int base_e = blockIdx.x * 4096;
    int d[16], s[16];
#pragma unroll
    for (int q = 0; q < 4; ++q) {
        int e0 = base_e + q * 1024 + t * 4;
        int4 dv = make_int4(-1, -1, -1, -1), sv = make_int4(0, 0, 0, 0);
        if (e0 + 3 < E) {
            dv = *(const int4*)&dst[e0];
            sv = *(const int4*)&src[e0];
        } else if (e0 < E) {
            int m = E - e0;
            const int* dp = &dst[e0];
            const int* sp = &src[e0];
            int* dvp = (int*)&dv;
            int* svp = (int*)&sv;
            for (int j = 0; j < m; ++j) { dvp[j] = dp[j]; svp[j] = sp[j]; }
        }
        *(int4*)&d[q * 4] = dv;
        *(int4*)&s[q * 4] = sv;
    }
#pragma unroll
    for (int it = 0; it < 16; ++it)
        if (d[it] >= 0) atomicAdd(&cnt[d[it] >> BUCKET_BITS], 1);
    __syncthreads();
    if (t < NB && cnt[t] > 0) rbase[t] = atomicAdd(&bucket_cursor[t], cnt[t]);
    __syncthreads();
#pragma unroll
    for (int it = 0; it < 16; ++it) {
        if (d[it] >= 0) {
            int b = d[it] >> BUCKET_BITS;
            int pos = atomicAdd(&rbase[b], 1);
            if (pos < cap)
                staging[(size_t)b * cap + pos] =
                    ((unsigned)(d[it] & (BUCKET_SZ - 1)) << 17) | ((unsigned)s[it] & 0x1FFFFu);
        }
    }
}

// ---------------------------------------------------------------- fused: b_build blocks [0,nbuild) || gemm1 blocks [nbuild, nbuild+nb1)
// Roles have compatible profiles: both 512 threads; build's 6.2KB LDS carved from gemm1's 36.9KB tile.
__global__ __launch_bounds__(512) void build_gemm1(const unsigned* __restrict__ staging,
                                                   const int* __restrict__ bucket_cursor,
                                                   int* __restrict__ row_start,
                                                   int* __restrict__ csr_src, int N, int E,
                                                   int NB, int cap, int nbuild,
                                                   const float* __restrict__ x,
                                                   const u16* __restrict__ W1bT,
                                                   u16* __restrict__ featb,
                                                   float* __restrict__ el,
                                                   float* __restrict__ er) {
    __shared__ u16 ws[144 * 128];
    __shared__ int sh_cbase, sh_cnt;
    int t = threadIdx.x;
    if (blockIdx.x < nbuild) {
        // ---------------- b_build role (512 threads, LDS carved from ws)
        int* deg = (int*)ws;        // 512 ints
        int* cur = deg + 512;       // 512 ints
        int* tmp = cur + 512;       // 512 ints
        int b = blockIdx.x;
        int v = (t < NB) ? bucket_cursor[t] : 0;
        tmp[t] = v;
        __syncthreads();
        for (int off = 1; off < 512; off <<= 1) {
            int x2 = (t >= off) ? tmp[t - off] : 0;
            __syncthreads();
            tmp[t] += x2;
            __syncthreads();
        }
        if (t == b) { sh_cbase = tmp[t] - v; sh_cnt = min(v, cap); }
        if (b == 0 && t == 0) row_start[N] = E;
        __syncthreads();
        int cbase = sh_cbase, cnt = sh_cnt;
        int node0 = b << BUCKET_BITS;
        int nn = min(BUCKET_SZ, N - node0);
        deg[t] = 0;
        __syncthreads();
        const unsigned* st = &staging[(size_t)b * cap];
        for (int i = t; i < cnt; i += 512) atomicAdd(&deg[st[i] >> 17], 1);
        __syncthreads();
        int a0 = (t < nn) ? deg[t] : 0;
        tmp[t] = a0;
        __syncthreads();
        for (int off = 1; off < 512; off <<= 1) {
            int x2 = (t >= off) ? tmp[t - off] : 0;
            __syncthreads();
            tmp[t] += x2;
            __syncthreads();
        }
        int excl = tmp[t] - a0;
        if (t < nn) { row_start[node0 + t] = cbase + excl; cur[t] = excl; }
        __syncthreads();
        for (int i = t; i < cnt; i += 512) {
            unsigned e = st[i];
            int p = atomicAdd(&cur[e >> 17], 1);
            csr_src[cbase + p] = (int)(e & 0x1FFFFu);
        }
        return;
    }
    // ---------------- gemm1 role (512 threads, 128-row blocks)
    int base = (blockIdx.x - nbuild) * 128;
    for (int idx = t; idx < 2304; idx += 512) {
        int c = idx >> 4, k8 = (idx & 15) * 8;
        *(s16x8*)&ws[SWZ(c * 128 + k8, c)] = *(const s16x8*)&W1bT[c * 128 + k8];
    }
    int wid = t >> 6, lane = t & 63;
    int lr = lane & 15, lg = lane >> 4;
    int row0 = wid * 16;
    int grow = base + row0 + lr;
    bool rowok = grow < N;
    int crow = rowok ? grow : 0;
    s16x8 afr[4];
#pragma unroll
    for (int kt = 0; kt < 4; ++kt) {
        const float4* px = (const float4*)&x[(size_t)crow * 128 + kt * 32 + lg * 8];
        float4 v0 = px[0], v1 = px[1];
        unsigned p[4] = {cvt_pk_bf16(v0.x, v0.y), cvt_pk_bf16(v0.z, v0.w),
                         cvt_pk_bf16(v1.x, v1.y), cvt_pk_bf16(v1.z, v1.w)};
        if (!rowok) { p[0] = p[1] = p[2] = p[3] = 0; }
        afr[kt] = *(s16x8*)p;
    }
    __syncthreads();
    f32x4 acc[9];
#pragma unroll
    for (int ct = 0; ct < 9; ++ct) acc[ct] = (f32x4){0.f, 0.f, 0.f, 0.f};
#pragma unroll
    for (int ct = 0; ct < 9; ++ct) {
#pragma unroll
        for (int kt = 0; kt < 4; ++kt) {
            int c = ct * 16 + lr, k = kt * 32 + lg * 8;
            s16x8 bfr = *(const s16x8*)&ws[SWZ(c * 128 + k, c)];
            acc[ct] = __builtin_amdgcn_mfma_f32_16x16x32_bf16(afr[kt], bfr, acc[ct], 0, 0, 0);
        }
    }
#pragma unroll
    for (int ct = 0; ct < 9; ++ct) {
#pragma unroll
        for (int r = 0; r < 4; ++r) {
            int row = base + row0 + lg * 4 + r;
            if (row >= N) continue;
            float v = acc[ct][r];
            if (ct < 8) {
                featb[(size_t)row * 128 + ct * 16 + lr] = f2bf(v);
            } else {
                if (lr < 4) el[row * 4 + lr] = v;
                else if (lr < 8) er[row * 4 + (lr - 4)] = v;
            }
        }
    }
}

// ---------------------------------------------------------------- agg layer 1 (r8/r12 version — untouched, at roofline)
__global__ __launch_bounds__(256) void agg1(const int* __restrict__ row_start,
                                            const int* __restrict__ csr_src,
                                            const float* __restrict__ el1,
                                            const float* __restrict__ er1,
                                            const u16* __restrict__ featb,
                                            const float* __restrict__ b1,
                                            u16* __restrict__ hb, int n) {
    __shared__ float us[4][64][4];   // [wave][edge][head]
    __shared__ int sns[4][64];
    int wid = threadIdx.x >> 6, lane = threadIdx.x & 63;
    int node = blockIdx.x * 4 + wid;
    if (node >= n) return;
    int slot = lane >> 4, dg = lane & 15;
    int h = dg >> 2;
    int rs = row_start[node], re = row_start[node + 1];
    float4 er4 = *(const float4*)&er1[node * 4];
    float acc[8] = {};
    float z = 0.f;
    for (int ts = rs; ts < re; ts += 64) {
        int cnt = min(64, re - ts);
        if (lane < cnt) {
            int sn = min(max(csr_src[ts + lane], 0), n - 1);
            sns[wid][lane] = sn;
            float4 elv = *(const float4*)&el1[sn * 4];
            float e0 = elv.x + er4.x, e1 = elv.y + er4.y;
            float e2 = elv.z + er4.z, e3 = elv.w + er4.w;
            e0 = e0 > 0.f ? e0 : NEG_SLOPE * e0;
            e1 = e1 > 0.f ? e1 : NEG_SLOPE * e1;
            e2 = e2 > 0.f ? e2 : NEG_SLOPE * e2;
            e3 = e3 > 0.f ? e3 : NEG_SLOPE * e3;
            *(float4*)&us[wid][lane][0] =
                make_float4(__expf(fminf(e0, 60.f)), __expf(fminf(e1, 60.f)),
                            __expf(fminf(e2, 60.f)), __expf(fminf(e3, 60.f)));
        }
        for (int e0i = 0; e0i < cnt; e0i += 8) {
            int ea = e0i + slot, eb = e0i + 4 + slot;
            bool va = ea < cnt, vb = eb < cnt;
            int ia = va ? ea : 0, ib = vb ? eb : 0;
            int sa = sns[wid][ia], sb = sns[wid][ib];
            float wa = va ? us[wid][ia][h] : 0.f;
            float wb = vb ? us[wid][ib][h] : 0.f;
            uint4 fa = *(const uint4*)&featb[(size_t)sa * 128 + dg * 8];
            uint4 fb = *(const uint4*)&featb[(size_t)sb * 128 + dg * 8];
            acc[0] += wa * __uint_as_float(fa.x << 16);
            acc[1] += wa * __uint_as_float(fa.x & 0xffff0000u);
            acc[2] += wa * __uint_as_float(fa.y << 16);
            acc[3] += wa * __uint_as_float(fa.y & 0xffff0000u);
            acc[4] += wa * __uint_as_float(fa.z << 16);
            acc[5] += wa * __uint_as_float(fa.z & 0xffff0000u);
            acc[6] += wa * __uint_as_float(fa.w << 16);
            acc[7] += wa * __uint_as_float(fa.w & 0xffff0000u);
            z += wa;
            acc[0] += wb * __uint_as_float(fb.x << 16);
            acc[1] += wb * __uint_as_float(fb.x & 0xffff0000u);
            acc[2] += wb * __uint_as_float(fb.y << 16);
            acc[3] += wb * __uint_as_float(fb.y & 0xffff0000u);
            acc[4] += wb * __uint_as_float(fb.z << 16);
            acc[5] += wb * __uint_as_float(fb.z & 0xffff0000u);
            acc[6] += wb * __uint_as_float(fb.w << 16);
            acc[7] += wb * __uint_as_float(fb.w & 0xffff0000u);
            z += wb;
        }
    }
#pragma unroll
    for (int i = 0; i < 8; ++i) {
        acc[i] += __shfl_xor(acc[i], 16);
        acc[i] += __shfl_xor(acc[i], 32);
    }
    z += __shfl_xor(z, 16);
    z += __shfl_xor(z, 32);
    if (slot == 0) {
        float inv = (z > 0.f) ? 1.f / z : 0.f;
        float4 b0 = *(const float4*)&b1[dg * 8];
        float4 b4 = *(const float4*)&b1[dg * 8 + 4];
        float vv[8] = {acc[0] * inv + b0.x, acc[1] * inv + b0.y,
                       acc[2] * inv + b0.z, acc[3] * inv + b0.w,
                       acc[4] * inv + b4.x, acc[5] * inv + b4.y,
                       acc[6] * inv + b4.z, acc[7] * inv + b4.w};
        u16 o[8];
#pragma unroll
        for (int i = 0; i < 8; ++i) {
            float v = vv[i] > 0.f ? vv[i] : expm1f(vv[i]);
            o[i] = f2bf(v);
        }
        *(s16x8*)&hb[(size_t)node * 128 + dg * 8] = *(s16x8*)o;
    }
}

// ---------------------------------------------------------------- GEMM2 (MFMA): 512 threads, 128-row blocks, A from registers
__global__ __launch_bounds__(512) void gemm2_mfma(const u16* __restrict__ hb,
                                                  const u16* __restrict__ W2bT,
                                                  u16* __restrict__ feat2b,
                                                  float* __restrict__ el2,
                                                  float* __restrict__ er2, int n) {
    __shared__ u16 ws[32 * 128];
    int t = threadIdx.x;
    int base = blockIdx.x * 128;
    if (t < 512) {
        int c = t >> 4, k8 = (t & 15) * 8;
        *(s16x8*)&ws[SWZ(c * 128 + k8, c)] = *(const s16x8*)&W2bT[c * 128 + k8];
    }
    int wid = t >> 6, lane = t & 63;
    int lr = lane & 15, lg = lane >> 4;
    int row0 = wid * 16;
    int grow = base + row0 + lr;
    bool rowok = grow < n;
    int crow = rowok ? grow : 0;
    s16x8 afr[4];
#pragma unroll
    for (int kt = 0; kt < 4; ++kt) {
        s16x8 v = *(const s16x8*)&hb[(size_t)crow * 128 + kt * 32 + lg * 8];
        if (!rowok) v = (s16x8){0, 0, 0, 0, 0, 0, 0, 0};
        afr[kt] = v;
    }
    __syncthreads();
    f32x4 acc[2];
    acc[0] = (f32x4){0.f, 0.f, 0.f, 0.f};
    acc[1] = acc[0];
#pragma unroll
    for (int ct = 0; ct < 2; ++ct) {
#pragma unroll
        for (int kt = 0; kt < 4; ++kt) {
            int c = ct * 16 + lr, k = kt * 32 + lg * 8;
            s16x8 bfr = *(const s16x8*)&ws[SWZ(c * 128 + k, c)];
            acc[ct] = __builtin_amdgcn_mfma_f32_16x16x32_bf16(afr[kt], bfr, acc[ct], 0, 0, 0);
        }
    }
#pragma unroll
    for (int ct = 0; ct < 2; ++ct) {
#pragma unroll
        for (int r = 0; r < 4; ++r) {
            int row = base + row0 + lg * 4 + r;
            if (row >= n) continue;
            float v = acc[ct][r];
            if (ct == 0) {
                feat2b[(size_t)row * 16 + lr] = f2bf(v);
            } else {
                if (lr == 0) el2[row] = v;
                else if (lr == 1) er2[row] = v;
            }
        }
    }
}

// ---------------------------------------------------------------- agg layer 2: 2 nodes/wave, 2-edge unroll, grid-stride (r14 version)
__global__ __launch_bounds__(256) void agg2(const int* __restrict__ row_start,
                                            const int* __restrict__ csr_src,
                                            const float* __restrict__ el2,
                                            const float* __restrict__ er2,
                                            const u16* __restrict__ feat2b,
                                            const float* __restrict__ b2,
                                            float* __restrict__ out, int n) {
    int t = threadIdx.x;
    int wid = t >> 6, lane = t & 63;
    int sub = lane >> 5;
    int slot = (lane >> 2) & 7;
    int dq = lane & 3;
    int ngroups = (n + 7) >> 3;
    for (int grp = blockIdx.x; grp < ngroups; grp += gridDim.x) {
        int node = grp * 8 + wid * 2 + sub;
        if (node >= n) continue;
        int rs = row_start[node], re = row_start[node + 1];
        float er_n = er2[node];
        float a0 = 0.f, a1 = 0.f, a2 = 0.f, a3 = 0.f, z = 0.f;
        for (int ts = rs; ts < re; ts += 16) {
            int ea = ts + slot, eb = ts + 8 + slot;
            bool va = ea < re, vb = eb < re;
            int sa = va ? csr_src[ea] : 0;
            int sb = vb ? csr_src[eb] : 0;
            sa = min(max(sa, 0), n - 1);
            sb = min(max(sb, 0), n - 1);
            float eva = el2[sa] + er_n;
            float evb = el2[sb] + er_n;
            uint2 fa = *(const uint2*)&feat2b[(size_t)sa * 16 + dq * 4];
            uint2 fb = *(const uint2*)&feat2b[(size_t)sb * 16 + dq * 4];
            eva = eva > 0.f ? eva : NEG_SLOPE * eva;
            evb = evb > 0.f ? evb : NEG_SLOPE * evb;
            float wa = va ? __expf(fminf(eva, 60.f)) : 0.f;
            float wb = vb ? __expf(fminf(evb, 60.f)) : 0.f;
            a0 += wa * __uint_as_float(fa.x << 16) + wb * __uint_as_float(fb.x << 16);
            a1 += wa * __uint_as_float(fa.x & 0xffff0000u) + wb * __uint_as_float(fb.x & 0xffff0000u);
            a2 += wa * __uint_as_float(fa.y << 16) + wb * __uint_as_float(fb.y << 16);
            a3 += wa * __uint_as_float(fa.y & 0xffff0000u) + wb * __uint_as_float(fb.y & 0xffff0000u);
            z += wa + wb;
        }
#pragma unroll
        for (int o = 4; o <= 16; o <<= 1) {
            a0 += __shfl_xor(a0, o);
            a1 += __shfl_xor(a1, o);
            a2 += __shfl_xor(a2, o);
            a3 += __shfl_xor(a3, o);
            z += __shfl_xor(z, o);
        }
        if (slot == 0) {
            float inv = (z > 0.f) ? 1.f / z : 0.f;
            float4 bv = *(const float4*)&b2[dq * 4];
            *(float4*)&out[(size_t)node * 16 + dq * 4] =
                make_float4(a0 * inv + bv.x, a1 * inv + bv.y, a2 * inv + bv.z, a3 * inv + bv.w);
        }
    }
}

// ---------------------------------------------------------------- launch
extern "C" void kernel_launch(void* const* d_in, const int* in_sizes, int n_in,
                              void* d_out, int out_size, void* d_ws, size_t ws_size,
                              hipStream_t stream) {
    const float* x   = (const float*)d_in[0];
    const int*   src = (const int*)d_in[1];
    const int*   dst = (const int*)d_in[2];
    const float* W1  = (const float*)d_in[3];
    const float* al1 = (const float*)d_in[4];
    const float* ar1 = (const float*)d_in[5];
    const float* b1  = (const float*)d_in[6];
    const float* W2  = (const float*)d_in[7];
    const float* al2 = (const float*)d_in[8];
    const float* ar2 = (const float*)d_in[9];
    const float* b2  = (const float*)d_in[10];
    float* out = (float*)d_out;

    const int N = in_sizes[0] / 128;
    const int E = in_sizes[1];
    const int NB = (N + BUCKET_SZ - 1) >> BUCKET_BITS;
    const int cap = ((2 * (E / NB)) + 255) & ~255;

    char* p = (char*)d_ws;
    auto alloc = [&](size_t bytes) {
        char* r = p;
        p += (bytes + 255) & ~(size_t)255;
        return r;
    };
    u16* W1bT   = (u16*)alloc(144 * 128 * 2);
    u16* W2bT   = (u16*)alloc(32 * 128 * 2);
    u16* feat1b = (u16*)alloc((size_t)N * 128 * 2);
    u16* hb     = (u16*)alloc((size_t)N * 128 * 2);
    u16* feat2b = (u16*)alloc((size_t)N * 16 * 2);
    float* el1  = (float*)alloc((size_t)N * 4 * 4);
    float* er1  = (float*)alloc((size_t)N * 4 * 4);
    float* el2v = (float*)alloc((size_t)N * 4);
    float* er2v = (float*)alloc((size_t)N * 4);
    int* row_start     = (int*)alloc((size_t)(N + 1) * 4);
    int* csr_src       = (int*)alloc((size_t)E * 4);
    int* bucket_cursor = (int*)alloc((size_t)NB * 4);
    unsigned* staging  = (unsigned*)alloc((size_t)NB * cap * 4);

    (void)hipMemsetAsync(bucket_cursor, 0, (size_t)NB * 4, stream);

    int nsc = (E + 4095) / 4096;
    scatter_prep<<<nsc + PREP_BLOCKS, 256, 0, stream>>>(src, dst, bucket_cursor, staging,
                                                        E, NB, cap, nsc,
                                                        W1, al1, ar1, W2, al2, ar2, W1bT, W2bT);

    int nb1 = (N + 127) / 128;
    build_gemm1<<<NB + nb1, 512, 0, stream>>>(staging, bucket_cursor, row_start, csr_src,
                                              N, E, NB, cap, NB,
                                              x, W1bT, feat1b, el1, er1);

    int nodeblk = (N + 3) / 4;
    agg1<<<nodeblk, 256, 0, stream>>>(row_start, csr_src, el1, er1, feat1b, b1, hb, N);
    gemm2_mfma<<<nb1, 512, 0, stream>>>(hb, W2bT, feat2b, el2v, er2v, N);
    agg2<<<2048, 256, 0, stream>>>(row_start, csr_src, el2v, er2v, feat2b, b2, out, N);
}